// Round 6
// baseline (1702.424 us; speedup 1.0000x reference)
//
#include <hip/hip_runtime.h>

// ---------------------------------------------------------------------------
// RatingLayer: 2-round fully-connected 2-node GRU + linear head.
// One [24576,4096]^T bf16 GEMM per round (W_ih column-half-swapped + stacked
// with W_hh). Round 6: (a) non-temporal C stores/loads (stop L3 thrash of W),
// (b) deeper vmcnt ladder: gates vmcnt(10)@ph1 / vmcnt(8)@ph3 give every
// load >=6 phases (~900cy) of flight. Quadrant phases + T2 swizzle retained.
// ---------------------------------------------------------------------------

typedef __bf16 bf16x8 __attribute__((ext_vector_type(8)));
typedef float  f32x4  __attribute__((ext_vector_type(4)));
typedef unsigned short u16x4 __attribute__((ext_vector_type(4)));

#define HH    4096
#define NI_D  2048
#define N3H   12288
#define N6H   24576
#define BSZ   4096
#define BM    256
#define BN    256
#define BK    64
#define MT    (BSZ / BM)     // 16
#define NT    (N6H / BN)     // 96
#define GRID_GEMM (MT * NT)  // 1536
#define NKT   (HH / BK)      // 64 K-tiles

#define NB_W  98304
#define NB_C  16384

__device__ __forceinline__ unsigned short f2bf(float f) {
  unsigned u = __float_as_uint(f);
  u += 0x7FFFu + ((u >> 16) & 1u);
  return (unsigned short)(u >> 16);
}
__device__ __forceinline__ float bf2f(unsigned short s) {
  return __uint_as_float(((unsigned)s) << 16);
}

__device__ __forceinline__ void gload16(const void* g, void* l) {
  void* gv = (void*)g;
  __builtin_amdgcn_global_load_lds(
      (__attribute__((address_space(1))) unsigned int*)gv,
      (__attribute__((address_space(3))) unsigned int*)l,
      16, 0, 0);
}

__device__ __forceinline__ u16x4 ntload4(const unsigned short* p) {
  return __builtin_nontemporal_load((const u16x4*)p);
}

// --- fused prep: Wc[j][k] = bf16(j<3H ? W_ih[j][(k+NI)%H] : W_hh[j-3H][k]);
//     hb = bf16(features)
__global__ void __launch_bounds__(256)
prep(const float* __restrict__ Wih, const float* __restrict__ Whh,
     const float* __restrict__ feat,
     unsigned short* __restrict__ Wc, unsigned short* __restrict__ hb)
{
  int bid = blockIdx.x;
  if (bid < NB_W) {
    int idx = (bid * 256 + threadIdx.x) << 2;
    int j = idx >> 12;
    int k = idx & 4095;
    const float* src;
    if (j < N3H) src = Wih + (size_t)j * HH + ((k + NI_D) & (HH - 1));
    else         src = Whh + (size_t)(j - N3H) * HH + k;
    f32x4 v = *(const f32x4*)src;
    u16x4 o = { f2bf(v[0]), f2bf(v[1]), f2bf(v[2]), f2bf(v[3]) };
    *(u16x4*)(Wc + idx) = o;
  } else {
    int i = ((bid - NB_W) * 256 + threadIdx.x) << 2;
    f32x4 v = *(const f32x4*)(feat + i);
    u16x4 o = { f2bf(v[0]), f2bf(v[1]), f2bf(v[2]), f2bf(v[3]) };
    *(u16x4*)(hb + i) = o;
  }
}

// ---------------------------------------------------------------------------
// GEMM helpers. LDS: buf d: A at d*32768 (256 rows x 128 B), B at 65536+d*32768.
// Granule g = 64 rows = one gload16 per thread (8 KB). Linear LDS dest; global
// source column pre-swizzled by ((row&7)<<4) (rule 21 both-sides).
// ---------------------------------------------------------------------------
__device__ __forceinline__ void stageA(const char* a_base, char* lds, int ldst,
                                       int d, int kt, int g) {
  int kc = (kt < NKT) ? kt : 0;                 // dummy tail loads, race-safe
  gload16(a_base + (size_t)kc * 128 + (size_t)g * 524288,
          lds + d * 32768 + g * 8192 + ldst);
}
__device__ __forceinline__ void stageB(const char* b_base, char* lds, int ldst,
                                       int d, int kt, int g) {
  int kc = (kt < NKT) ? kt : 0;
  gload16(b_base + (size_t)kc * 128 + (size_t)g * 524288,
          lds + 65536 + d * 32768 + g * 8192 + ldst);
}

// One C-quadrant over full K=64: 16 MFMAs into acc[MB..MB+3][NB..NB+1].
template <int MB, int NB>
__device__ __forceinline__ void mfmaQ(f32x4 (&acc)[8][4],
                                      const bf16x8 (&af)[4][2],
                                      const bf16x8 (&bf)[2][2]) {
  __builtin_amdgcn_s_setprio(1);
#pragma unroll
  for (int ks = 0; ks < 2; ++ks)
#pragma unroll
    for (int mf = 0; mf < 4; ++mf)
#pragma unroll
      for (int nf = 0; nf < 2; ++nf)
        acc[MB + mf][NB + nf] = __builtin_amdgcn_mfma_f32_16x16x32_bf16(
            af[mf][ks], bf[nf][ks], acc[MB + mf][NB + nf], 0, 0, 0);
  __builtin_amdgcn_s_setprio(0);
}

#define BAR   __builtin_amdgcn_s_barrier()
#define LGKM0 do { asm volatile("s_waitcnt lgkmcnt(0)" ::: "memory");          \
                   __builtin_amdgcn_sched_barrier(0); } while (0)

// One K-tile (4 quadrant phases). A frags 4-7 = granules G1(wm0)/G3(wm1);
// frags 0-3 = G0/G2.
// Stage ledger (per-wave issue order, race-verified):
//   [t-1 ph0] A(t)G0,G2    [t-1 ph1] A(t+1)G1,G3   [t-1 ph2/3] B(t+1)G0-3
//   [t   ph0] A(t+1)G0,G2  [t   ph1] A(t+2)G1,G3   [t   ph2/3] B(t+2)G0-3
// Gates: ph1-end vmcnt(10) -> A(t)G0,G2 landed (needed ph2; 6 phases flight).
//        ph3-end vmcnt(8)  -> A(t+1)G1,G3 + B(t+1) landed (next tile ph0/1;
//        >=7 phases flight). Never vmcnt(0) in loop.
template <int D>
__device__ __forceinline__ void kblock(char* lds, const char* a_base,
                                       const char* b_base, int ldst,
                                       int aro, int bro, int offk0, int offk1,
                                       int t1, int t2, f32x4 (&acc)[8][4]) {
  const char* LA = lds + D * 32768 + aro;
  const char* LB = lds + 65536 + D * 32768 + bro;
  bf16x8 a47[4][2], a03[4][2], b01[2][2], b23[2][2];

  // ---- ph0: Q(m4-7, n0-1). 12 ds_reads; stage A(t1) G0,G2 -> D^1.
#pragma unroll
  for (int mf = 0; mf < 4; ++mf) {
    a47[mf][0] = *(const bf16x8*)(LA + (4 + mf) * 2048 + offk0);
    a47[mf][1] = *(const bf16x8*)(LA + (4 + mf) * 2048 + offk1);
  }
#pragma unroll
  for (int nf = 0; nf < 2; ++nf) {
    b01[nf][0] = *(const bf16x8*)(LB + nf * 2048 + offk0);
    b01[nf][1] = *(const bf16x8*)(LB + nf * 2048 + offk1);
  }
  stageA(a_base, lds, ldst, D ^ 1, t1, 0);
  stageA(a_base, lds, ldst, D ^ 1, t1, 2);
  asm volatile("s_waitcnt lgkmcnt(8)" ::: "memory");  // throttle (12 reads)
  BAR; LGKM0;
  mfmaQ<4, 0>(acc, a47, b01);
  BAR;

  // ---- ph1: Q(m4-7, n2-3). 4 ds_reads; stage A(t2) G1,G3 -> D; gate 10.
#pragma unroll
  for (int nf = 0; nf < 2; ++nf) {
    b23[nf][0] = *(const bf16x8*)(LB + (2 + nf) * 2048 + offk0);
    b23[nf][1] = *(const bf16x8*)(LB + (2 + nf) * 2048 + offk1);
  }
  stageA(a_base, lds, ldst, D, t2, 1);
  stageA(a_base, lds, ldst, D, t2, 3);
  BAR; LGKM0;
  mfmaQ<4, 2>(acc, a47, b23);
  asm volatile("s_waitcnt vmcnt(10)" ::: "memory");   // A(t)G0,G2 landed
  BAR;

  // ---- ph2: Q(m0-3, n0-1). 8 ds_reads; stage B(t2) G0,G1 -> D.
#pragma unroll
  for (int mf = 0; mf < 4; ++mf) {
    a03[mf][0] = *(const bf16x8*)(LA + mf * 2048 + offk0);
    a03[mf][1] = *(const bf16x8*)(LA + mf * 2048 + offk1);
  }
  stageB(b_base, lds, ldst, D, t2, 0);
  stageB(b_base, lds, ldst, D, t2, 1);
  BAR; LGKM0;
  mfmaQ<0, 0>(acc, a03, b01);
  BAR;

  // ---- ph3: Q(m0-3, n2-3). 0 ds_reads; stage B(t2) G2,G3 -> D; gate 8.
  stageB(b_base, lds, ldst, D, t2, 2);
  stageB(b_base, lds, ldst, D, t2, 3);
  BAR;
  mfmaQ<0, 2>(acc, a03, b23);
  asm volatile("s_waitcnt vmcnt(8)" ::: "memory");    // next tile's a47+B landed
  BAR;
}

// ---------------------------------------------------------------------------
// C[4096, 24576] bf16 = A[4096,4096] * B[24576,4096]^T   (bf16 in, bf16 out)
// 256x256 tile, BK=64, 512 threads (8 waves, 2Mx4N), LDS 128 KB (2 dbuf).
// ---------------------------------------------------------------------------
__global__ void __launch_bounds__(512, 2)
gemm_bt(const unsigned short* __restrict__ A,
        const unsigned short* __restrict__ B,
        unsigned short* __restrict__ C)
{
  __shared__ alignas(16) char lds[131072];

  int bid = blockIdx.x;
  int wg  = (bid & 7) * (GRID_GEMM / 8) + (bid >> 3);  // XCD swizzle, 1536%8==0
  int nt  = wg / MT;          // n-major: 16 consecutive wg share one W panel
  int mt  = wg % MT;
  int m0  = mt * BM;
  int n0  = nt * BN;

  int t  = threadIdx.x;
  int wv = t >> 6;
  int l  = t & 63;
  int wm = wv >> 2;
  int wn = wv & 3;

  // staging: thread covers row rloc of a 64-row granule, 16B chunk (l&7),
  // source column XOR-preswizzled by row&7 = l>>3.
  int rloc   = wv * 8 + (l >> 3);
  int sg_col = ((l & 7) ^ (l >> 3)) << 4;
  const char* a_base = (const char*)A + (size_t)(m0 + rloc) * 8192 + sg_col;
  const char* b_base = (const char*)B + (size_t)(n0 + rloc) * 8192 + sg_col;
  int ldst = wv * 1024;       // wave-uniform LDS dest offset within granule

  // read-side swizzled offsets
  int offk0 = ((l >> 4) << 4) ^ ((l & 7) << 4);
  int offk1 = offk0 ^ 64;
  int aro = (wm * 128 + (l & 15)) * 128;
  int bro = (wn * 64  + (l & 15)) * 128;

  f32x4 acc[8][4] = {};

  // prologue, steady-state issue order. Retired set before tile0: A(0)G1,G3 +
  // B(0) (6 loads); in-flight (8): A(0)G0,G2 + A(1)G1,G3 + B(1)G0-3.
  stageA(a_base, lds, ldst, 0, 0, 1);
  stageA(a_base, lds, ldst, 0, 0, 3);
#pragma unroll
  for (int g = 0; g < 4; ++g) stageB(b_base, lds, ldst, 0, 0, g);
  stageA(a_base, lds, ldst, 0, 0, 0);
  stageA(a_base, lds, ldst, 0, 0, 2);
  stageA(a_base, lds, ldst, 1, 1, 1);
  stageA(a_base, lds, ldst, 1, 1, 3);
#pragma unroll
  for (int g = 0; g < 4; ++g) stageB(b_base, lds, ldst, 1, 1, g);
  asm volatile("s_waitcnt vmcnt(8)" ::: "memory");
  BAR;

#pragma unroll 1
  for (int tt = 0; tt < NKT; tt += 2) {
    kblock<0>(lds, a_base, b_base, ldst, aro, bro, offk0, offk1,
              tt + 1, tt + 2, acc);
    kblock<1>(lds, a_base, b_base, ldst, aro, bro, offk0, offk1,
              tt + 2, tt + 3, acc);
  }
  asm volatile("s_waitcnt vmcnt(0)" ::: "memory");  // drain dummy tail loads

  // C-write: frag layout col = lane&15, row = (lane>>4)*4 + reg (m89).
  // Non-temporal: C is read exactly once (by gru); keep W resident in L3.
  int crow = m0 + wm * 128 + ((l >> 4) << 2);
  int ccol = n0 + wn * 64 + (l & 15);
#pragma unroll
  for (int mf = 0; mf < 8; ++mf)
#pragma unroll
    for (int nf = 0; nf < 4; ++nf)
#pragma unroll
      for (int i = 0; i < 4; ++i)
        __builtin_nontemporal_store(
            f2bf(acc[mf][nf][i]),
            &C[(size_t)(crow + mf * 16 + i) * N6H + (ccol + nf * 16)]);
}

// --- round-1 GRU: h_old = features (f32); writes h1 as bf16 only.
__global__ void __launch_bounds__(256)
gru1(const unsigned short* __restrict__ C, const float* __restrict__ h_old,
     const float* __restrict__ b_ih, const float* __restrict__ b_hh,
     unsigned short* __restrict__ h_bf)
{
  int idx = blockIdx.x * 256 + threadIdx.x;
  int b = idx >> 10;
  int j = (idx & 1023) << 2;
  const unsigned short* Cr = C + (size_t)b * N6H;
  u16x4 gir = ntload4(Cr + j);
  u16x4 giz = ntload4(Cr + HH + j);
  u16x4 gin = ntload4(Cr + 2 * HH + j);
  u16x4 ghr = ntload4(Cr + 3 * HH + j);
  u16x4 ghz = ntload4(Cr + 4 * HH + j);
  u16x4 ghn = ntload4(Cr + 5 * HH + j);
  f32x4 bir = *(const f32x4*)(b_ih + j);
  f32x4 biz = *(const f32x4*)(b_ih + HH + j);
  f32x4 bin = *(const f32x4*)(b_ih + 2 * HH + j);
  f32x4 bhr = *(const f32x4*)(b_hh + j);
  f32x4 bhz = *(const f32x4*)(b_hh + HH + j);
  f32x4 bhn = *(const f32x4*)(b_hh + 2 * HH + j);
  f32x4 ho  = *(const f32x4*)(h_old + (size_t)b * HH + j);
  u16x4 hb;
#pragma unroll
  for (int e = 0; e < 4; ++e) {
    float r = 1.f / (1.f + expf(-(bf2f(gir[e]) + bir[e] + bf2f(ghr[e]) + bhr[e])));
    float z = 1.f / (1.f + expf(-(bf2f(giz[e]) + biz[e] + bf2f(ghz[e]) + bhz[e])));
    float n = tanhf(bf2f(gin[e]) + bin[e] + r * (bf2f(ghn[e]) + bhn[e]));
    hb[e] = f2bf((1.f - z) * n + z * ho[e]);
  }
  *(u16x4*)(h_bf + (size_t)b * HH + j) = hb;
}

// --- round-2 GRU fused with FC head: h_old = h1 (bf16); per-block partial
// dot(h2, fc_w) -> atomicAdd(out[b]). out zeroed by memset each call.
__global__ void __launch_bounds__(256)
gru2_fc(const unsigned short* __restrict__ C,
        const unsigned short* __restrict__ h_old_bf,
        const float* __restrict__ b_ih, const float* __restrict__ b_hh,
        const float* __restrict__ fcw, const float* __restrict__ fcb,
        float* __restrict__ out)
{
  int idx = blockIdx.x * 256 + threadIdx.x;
  int b = idx >> 10;
  int j = (idx & 1023) << 2;
  const unsigned short* Cr = C + (size_t)b * N6H;
  u16x4 gir = ntload4(Cr + j);
  u16x4 giz = ntload4(Cr + HH + j);
  u16x4 gin = ntload4(Cr + 2 * HH + j);
  u16x4 ghr = ntload4(Cr + 3 * HH + j);
  u16x4 ghz = ntload4(Cr + 4 * HH + j);
  u16x4 ghn = ntload4(Cr + 5 * HH + j);
  f32x4 bir = *(const f32x4*)(b_ih + j);
  f32x4 biz = *(const f32x4*)(b_ih + HH + j);
  f32x4 bin = *(const f32x4*)(b_ih + 2 * HH + j);
  f32x4 bhr = *(const f32x4*)(b_hh + j);
  f32x4 bhz = *(const f32x4*)(b_hh + HH + j);
  f32x4 bhn = *(const f32x4*)(b_hh + 2 * HH + j);
  u16x4 hob = *(const u16x4*)(h_old_bf + (size_t)b * HH + j);
  f32x4 fw  = *(const f32x4*)(fcw + j);
  float s = 0.f;
#pragma unroll
  for (int e = 0; e < 4; ++e) {
    float r = 1.f / (1.f + expf(-(bf2f(gir[e]) + bir[e] + bf2f(ghr[e]) + bhr[e])));
    float z = 1.f / (1.f + expf(-(bf2f(giz[e]) + biz[e] + bf2f(ghz[e]) + bhz[e])));
    float n = tanhf(bf2f(gin[e]) + bin[e] + r * (bf2f(ghn[e]) + bhn[e]));
    float h = (1.f - z) * n + z * bf2f(hob[e]);
    s += h * fw[e];
  }
#pragma unroll
  for (int off = 32; off > 0; off >>= 1) s += __shfl_down(s, off);
  __shared__ float red[4];
  if ((threadIdx.x & 63) == 0) red[threadIdx.x >> 6] = s;
  __syncthreads();
  if (threadIdx.x == 0) {
    float v = red[0] + red[1] + red[2] + red[3];
    if ((blockIdx.x & 3) == 0) v += fcb[0];
    atomicAdd(&out[b], v);
  }
}

extern "C" void kernel_launch(void* const* d_in, const int* in_sizes, int n_in,
                              void* d_out, int out_size, void* d_ws, size_t ws_size,
                              hipStream_t stream)
{
  const float* feat = (const float*)d_in[0];
  const float* Wih  = (const float*)d_in[1];
  const float* bih  = (const float*)d_in[2];
  const float* Whh  = (const float*)d_in[3];
  const float* bhh  = (const float*)d_in[4];
  const float* fcw  = (const float*)d_in[5];
  const float* fcb  = (const float*)d_in[6];
  float* out = (float*)d_out;

  char* ws = (char*)d_ws;
  unsigned short* Wc   = (unsigned short*)ws;                    // 201326592 B
  unsigned short* Cbuf = (unsigned short*)(ws + 201326592);      // 201326592 B
  unsigned short* hb   = (unsigned short*)(ws + 402653184);      //  33554432 B
  // total: 436207616 B

  hipMemsetAsync(out, 0, (size_t)out_size * sizeof(float), stream);
  prep<<<NB_W + NB_C, 256, 0, stream>>>(Wih, Whh, feat, Wc, hb);

  gemm_bt<<<GRID_GEMM, 512, 0, stream>>>(hb, Wc, Cbuf);
  gru1<<<16384, 256, 0, stream>>>(Cbuf, feat, bih, bhh, hb);

  gemm_bt<<<GRID_GEMM, 512, 0, stream>>>(hb, Wc, Cbuf);
  gru2_fc<<<16384, 256, 0, stream>>>(Cbuf, hb, bih, bhh, fcw, fcb, out);
}

// Round 7
// 1502.539 us; speedup vs baseline: 1.1330x; 1.1330x over previous
//
#include <hip/hip_runtime.h>

// ---------------------------------------------------------------------------
// RatingLayer: 2-round fully-connected 2-node GRU + linear head.
// One [24576,4096]^T bf16 GEMM per round. Round 7: read-ahead phase schedule
// (issue next phase's ds_reads before current phase's MFMA; 1 barrier/phase;
// counted vmcnt(6) gates). nt-stores of r6 reverted (partial-line HBM writes).
// ---------------------------------------------------------------------------

typedef __bf16 bf16x8 __attribute__((ext_vector_type(8)));
typedef float  f32x4  __attribute__((ext_vector_type(4)));
typedef unsigned short u16x4 __attribute__((ext_vector_type(4)));

#define HH    4096
#define NI_D  2048
#define N3H   12288
#define N6H   24576
#define BSZ   4096
#define BM    256
#define BN    256
#define BK    64
#define MT    (BSZ / BM)     // 16
#define NT    (N6H / BN)     // 96
#define GRID_GEMM (MT * NT)  // 1536
#define NKT   (HH / BK)      // 64 K-tiles

#define NB_W  98304
#define NB_C  16384

__device__ __forceinline__ unsigned short f2bf(float f) {
  unsigned u = __float_as_uint(f);
  u += 0x7FFFu + ((u >> 16) & 1u);
  return (unsigned short)(u >> 16);
}
__device__ __forceinline__ float bf2f(unsigned short s) {
  return __uint_as_float(((unsigned)s) << 16);
}

__device__ __forceinline__ void gload16(const void* g, void* l) {
  void* gv = (void*)g;
  __builtin_amdgcn_global_load_lds(
      (__attribute__((address_space(1))) unsigned int*)gv,
      (__attribute__((address_space(3))) unsigned int*)l,
      16, 0, 0);
}

// --- fused prep: Wc[j][k] = bf16(j<3H ? W_ih[j][(k+NI)%H] : W_hh[j-3H][k]);
//     hb = bf16(features)
__global__ void __launch_bounds__(256)
prep(const float* __restrict__ Wih, const float* __restrict__ Whh,
     const float* __restrict__ feat,
     unsigned short* __restrict__ Wc, unsigned short* __restrict__ hb)
{
  int bid = blockIdx.x;
  if (bid < NB_W) {
    int idx = (bid * 256 + threadIdx.x) << 2;
    int j = idx >> 12;
    int k = idx & 4095;
    const float* src;
    if (j < N3H) src = Wih + (size_t)j * HH + ((k + NI_D) & (HH - 1));
    else         src = Whh + (size_t)(j - N3H) * HH + k;
    f32x4 v = *(const f32x4*)src;
    u16x4 o = { f2bf(v[0]), f2bf(v[1]), f2bf(v[2]), f2bf(v[3]) };
    *(u16x4*)(Wc + idx) = o;
  } else {
    int i = ((bid - NB_W) * 256 + threadIdx.x) << 2;
    f32x4 v = *(const f32x4*)(feat + i);
    u16x4 o = { f2bf(v[0]), f2bf(v[1]), f2bf(v[2]), f2bf(v[3]) };
    *(u16x4*)(hb + i) = o;
  }
}

// ---------------------------------------------------------------------------
// GEMM helpers. LDS: buf d: A at d*32768 (256 rows x 128 B), B at 65536+d*32768.
// Granule g = 64 rows = one gload16 per thread (8 KB). Linear LDS dest; global
// source column pre-swizzled by ((row&7)<<4) (rule 21 both-sides).
// A frags 4-7 live in granules G1(wm0)/G3(wm1); frags 0-3 in G0/G2.
// ---------------------------------------------------------------------------
__device__ __forceinline__ void stageA(const char* a_base, char* lds, int ldst,
                                       int d, int kt, int g) {
  int kc = (kt < NKT) ? kt : 0;                 // dummy tail loads, race-safe
  gload16(a_base + (size_t)kc * 128 + (size_t)g * 524288,
          lds + d * 32768 + g * 8192 + ldst);
}
__device__ __forceinline__ void stageB(const char* b_base, char* lds, int ldst,
                                       int d, int kt, int g) {
  int kc = (kt < NKT) ? kt : 0;
  gload16(b_base + (size_t)kc * 128 + (size_t)g * 524288,
          lds + 65536 + d * 32768 + g * 8192 + ldst);
}

// One C-quadrant over full K=64: 16 MFMAs into acc[MB..MB+3][NB..NB+1].
template <int MB, int NB>
__device__ __forceinline__ void mfmaQ(f32x4 (&acc)[8][4],
                                      const bf16x8 (&af)[4][2],
                                      const bf16x8 (&bf)[2][2]) {
  __builtin_amdgcn_s_setprio(1);
#pragma unroll
  for (int ks = 0; ks < 2; ++ks)
#pragma unroll
    for (int mf = 0; mf < 4; ++mf)
#pragma unroll
      for (int nf = 0; nf < 2; ++nf)
        acc[MB + mf][NB + nf] = __builtin_amdgcn_mfma_f32_16x16x32_bf16(
            af[mf][ks], bf[nf][ks], acc[MB + mf][NB + nf], 0, 0, 0);
  __builtin_amdgcn_s_setprio(0);
}

#define BAR   __builtin_amdgcn_s_barrier()
#define SB    __builtin_amdgcn_sched_barrier(0)
#define LGKM0 do { asm volatile("s_waitcnt lgkmcnt(0)" ::: "memory"); SB; } while (0)
#define VM6   asm volatile("s_waitcnt vmcnt(6)" ::: "memory")

// One K-tile, read-ahead schedule. On entry: a47c/b01c hold this tile's
// fragments (read during previous tile's ph3 from this tile's buffer, landed
// via ph0's LGKM0). ph3 fills a47n/b01n from buffer D^1 for the next tile.
// Stage ledger per wave (steady state):
//   ph0: A(t1)G0,G2 -> D^1 | ph1: A(t2)G1,G3 -> D | ph2: B(t2)G0,G1 -> D
//   ph3: B(t2)G2,G3 -> D
// Gates: ph0 vmcnt(6) retires (t-1)ph1-and-older -> a03(t) staging landed.
//        ph2 vmcnt(6) retires (t-1)ph3-and-older -> D^1 fully valid for ph3
//        reads. Region checks: every staged region's LDS reads completed a
//        barrier earlier (a47 region: ph0 LGKM0+bar before ph1 stage; b01:
//        ph0 LGKM0, staged ph2; b23: ph1 LGKM0, staged ph3).
template <int D>
__device__ __forceinline__ void kblock(char* lds, const char* a_base,
                                       const char* b_base, int ldst,
                                       int aro, int bro, int offk0, int offk1,
                                       int t1, int t2, f32x4 (&acc)[8][4],
                                       bf16x8 (&a47c)[4][2], bf16x8 (&b01c)[2][2],
                                       bf16x8 (&a47n)[4][2], bf16x8 (&b01n)[2][2]) {
  const char* LA  = lds + D * 32768 + aro;
  const char* LB  = lds + 65536 + D * 32768 + bro;
  const char* LAn = lds + (D ^ 1) * 32768 + aro;
  const char* LBn = lds + 65536 + (D ^ 1) * 32768 + bro;
  bf16x8 a03[4][2], b23[2][2];

  // ---- ph0: MFMA(a47,b01); read-ahead b23; stage A(t1)G0,G2 -> D^1.
  LGKM0;                                 // a47c,b01c landed
#pragma unroll
  for (int nf = 0; nf < 2; ++nf) {
    b23[nf][0] = *(const bf16x8*)(LB + (2 + nf) * 2048 + offk0);
    b23[nf][1] = *(const bf16x8*)(LB + (2 + nf) * 2048 + offk1);
  }
  stageA(a_base, lds, ldst, D ^ 1, t1, 0);
  stageA(a_base, lds, ldst, D ^ 1, t1, 2);
  SB;
  mfmaQ<4, 0>(acc, a47c, b01c);
  VM6;
  BAR;

  // ---- ph1: MFMA(a47,b23); read-ahead a03; stage A(t2)G1,G3 -> D.
  LGKM0;                                 // b23 landed (flew under ph0 MFMA)
#pragma unroll
  for (int mf = 0; mf < 4; ++mf) {
    a03[mf][0] = *(const bf16x8*)(LA + mf * 2048 + offk0);
    a03[mf][1] = *(const bf16x8*)(LA + mf * 2048 + offk1);
  }
  stageA(a_base, lds, ldst, D, t2, 1);
  stageA(a_base, lds, ldst, D, t2, 3);
  SB;
  mfmaQ<4, 2>(acc, a47c, b23);
  BAR;

  // ---- ph2: MFMA(a03,b01); stage B(t2)G0,G1 -> D; gate D^1 validity.
  LGKM0;                                 // a03 landed
  stageB(b_base, lds, ldst, D, t2, 0);
  stageB(b_base, lds, ldst, D, t2, 1);
  SB;
  mfmaQ<0, 0>(acc, a03, b01c);
  VM6;
  BAR;

  // ---- ph3: MFMA(a03,b23); read-ahead next tile's a47,b01 from D^1;
  //           stage B(t2)G2,G3 -> D.
#pragma unroll
  for (int mf = 0; mf < 4; ++mf) {
    a47n[mf][0] = *(const bf16x8*)(LAn + (4 + mf) * 2048 + offk0);
    a47n[mf][1] = *(const bf16x8*)(LAn + (4 + mf) * 2048 + offk1);
  }
#pragma unroll
  for (int nf = 0; nf < 2; ++nf) {
    b01n[nf][0] = *(const bf16x8*)(LBn + nf * 2048 + offk0);
    b01n[nf][1] = *(const bf16x8*)(LBn + nf * 2048 + offk1);
  }
  stageB(b_base, lds, ldst, D, t2, 2);
  stageB(b_base, lds, ldst, D, t2, 3);
  SB;
  mfmaQ<0, 2>(acc, a03, b23);
  BAR;
}

// ---------------------------------------------------------------------------
// C[4096, 24576] bf16 = A[4096,4096] * B[24576,4096]^T   (bf16 in, bf16 out)
// 256x256 tile, BK=64, 512 threads (8 waves, 2Mx4N), LDS 128 KB (2 dbuf).
// ---------------------------------------------------------------------------
__global__ void __launch_bounds__(512, 2)
gemm_bt(const unsigned short* __restrict__ A,
        const unsigned short* __restrict__ B,
        unsigned short* __restrict__ C)
{
  __shared__ alignas(16) char lds[131072];

  int bid = blockIdx.x;
  int wg  = (bid & 7) * (GRID_GEMM / 8) + (bid >> 3);  // XCD swizzle, 1536%8==0
  int nt  = wg / MT;          // n-major: 16 consecutive wg share one W panel
  int mt  = wg % MT;
  int m0  = mt * BM;
  int n0  = nt * BN;

  int t  = threadIdx.x;
  int wv = t >> 6;
  int l  = t & 63;
  int wm = wv >> 2;
  int wn = wv & 3;

  // staging: thread covers row rloc of a 64-row granule, 16B chunk (l&7),
  // source column XOR-preswizzled by row&7 = l>>3.
  int rloc   = wv * 8 + (l >> 3);
  int sg_col = ((l & 7) ^ (l >> 3)) << 4;
  const char* a_base = (const char*)A + (size_t)(m0 + rloc) * 8192 + sg_col;
  const char* b_base = (const char*)B + (size_t)(n0 + rloc) * 8192 + sg_col;
  int ldst = wv * 1024;       // wave-uniform LDS dest offset within granule

  // read-side swizzled offsets
  int offk0 = ((l >> 4) << 4) ^ ((l & 7) << 4);
  int offk1 = offk0 ^ 64;
  int aro = (wm * 128 + (l & 15)) * 128;
  int bro = (wn * 64  + (l & 15)) * 128;

  f32x4 acc[8][4] = {};
  bf16x8 a47A[4][2], b01A[2][2], a47B[4][2], b01B[2][2];

  // prologue: D0 complete (8 loads), then steady-state in-flight set
  // {A(1)G1,G3, B(1)G0-3} (6 loads). vmcnt(6) -> D0 landed. Then issue
  // tile0's ph0 fragments (a47A,b01A) from D0; ph0's LGKM0 gates them.
#pragma unroll
  for (int g = 0; g < 4; ++g) stageA(a_base, lds, ldst, 0, 0, g);
#pragma unroll
  for (int g = 0; g < 4; ++g) stageB(b_base, lds, ldst, 0, 0, g);
  stageA(a_base, lds, ldst, 1, 1, 1);
  stageA(a_base, lds, ldst, 1, 1, 3);
#pragma unroll
  for (int g = 0; g < 4; ++g) stageB(b_base, lds, ldst, 1, 1, g);
  asm volatile("s_waitcnt vmcnt(6)" ::: "memory");
  BAR;
  {
    const char* LA0 = lds + aro;
    const char* LB0 = lds + 65536 + bro;
#pragma unroll
    for (int mf = 0; mf < 4; ++mf) {
      a47A[mf][0] = *(const bf16x8*)(LA0 + (4 + mf) * 2048 + offk0);
      a47A[mf][1] = *(const bf16x8*)(LA0 + (4 + mf) * 2048 + offk1);
    }
#pragma unroll
    for (int nf = 0; nf < 2; ++nf) {
      b01A[nf][0] = *(const bf16x8*)(LB0 + nf * 2048 + offk0);
      b01A[nf][1] = *(const bf16x8*)(LB0 + nf * 2048 + offk1);
    }
  }

#pragma unroll 1
  for (int tt = 0; tt < NKT; tt += 2) {
    kblock<0>(lds, a_base, b_base, ldst, aro, bro, offk0, offk1,
              tt + 1, tt + 2, acc, a47A, b01A, a47B, b01B);
    kblock<1>(lds, a_base, b_base, ldst, aro, bro, offk0, offk1,
              tt + 2, tt + 3, acc, a47B, b01B, a47A, b01A);
  }
  asm volatile("s_waitcnt vmcnt(0) lgkmcnt(0)" ::: "memory");  // drain tails

  // C-write: frag layout col = lane&15, row = (lane>>4)*4 + reg (m89)
  int crow = m0 + wm * 128 + ((l >> 4) << 2);
  int ccol = n0 + wn * 64 + (l & 15);
#pragma unroll
  for (int mf = 0; mf < 8; ++mf)
#pragma unroll
    for (int nf = 0; nf < 4; ++nf)
#pragma unroll
      for (int i = 0; i < 4; ++i)
        C[(size_t)(crow + mf * 16 + i) * N6H + (ccol + nf * 16)] =
            f2bf(acc[mf][nf][i]);
}

// --- round-1 GRU: h_old = features (f32); writes h1 as bf16 only.
__global__ void __launch_bounds__(256)
gru1(const unsigned short* __restrict__ C, const float* __restrict__ h_old,
     const float* __restrict__ b_ih, const float* __restrict__ b_hh,
     unsigned short* __restrict__ h_bf)
{
  int idx = blockIdx.x * 256 + threadIdx.x;
  int b = idx >> 10;
  int j = (idx & 1023) << 2;
  const unsigned short* Cr = C + (size_t)b * N6H;
  u16x4 gir = *(const u16x4*)(Cr + j);
  u16x4 giz = *(const u16x4*)(Cr + HH + j);
  u16x4 gin = *(const u16x4*)(Cr + 2 * HH + j);
  u16x4 ghr = *(const u16x4*)(Cr + 3 * HH + j);
  u16x4 ghz = *(const u16x4*)(Cr + 4 * HH + j);
  u16x4 ghn = *(const u16x4*)(Cr + 5 * HH + j);
  f32x4 bir = *(const f32x4*)(b_ih + j);
  f32x4 biz = *(const f32x4*)(b_ih + HH + j);
  f32x4 bin = *(const f32x4*)(b_ih + 2 * HH + j);
  f32x4 bhr = *(const f32x4*)(b_hh + j);
  f32x4 bhz = *(const f32x4*)(b_hh + HH + j);
  f32x4 bhn = *(const f32x4*)(b_hh + 2 * HH + j);
  f32x4 ho  = *(const f32x4*)(h_old + (size_t)b * HH + j);
  u16x4 hb;
#pragma unroll
  for (int e = 0; e < 4; ++e) {
    float r = 1.f / (1.f + expf(-(bf2f(gir[e]) + bir[e] + bf2f(ghr[e]) + bhr[e])));
    float z = 1.f / (1.f + expf(-(bf2f(giz[e]) + biz[e] + bf2f(ghz[e]) + bhz[e])));
    float n = tanhf(bf2f(gin[e]) + bin[e] + r * (bf2f(ghn[e]) + bhn[e]));
    hb[e] = f2bf((1.f - z) * n + z * ho[e]);
  }
  *(u16x4*)(h_bf + (size_t)b * HH + j) = hb;
}

// --- round-2 GRU fused with FC head: h_old = h1 (bf16); per-block partial
// dot(h2, fc_w) -> atomicAdd(out[b]). out zeroed by memset each call.
__global__ void __launch_bounds__(256)
gru2_fc(const unsigned short* __restrict__ C,
        const unsigned short* __restrict__ h_old_bf,
        const float* __restrict__ b_ih, const float* __restrict__ b_hh,
        const float* __restrict__ fcw, const float* __restrict__ fcb,
        float* __restrict__ out)
{
  int idx = blockIdx.x * 256 + threadIdx.x;
  int b = idx >> 10;
  int j = (idx & 1023) << 2;
  const unsigned short* Cr = C + (size_t)b * N6H;
  u16x4 gir = *(const u16x4*)(Cr + j);
  u16x4 giz = *(const u16x4*)(Cr + HH + j);
  u16x4 gin = *(const u16x4*)(Cr + 2 * HH + j);
  u16x4 ghr = *(const u16x4*)(Cr + 3 * HH + j);
  u16x4 ghz = *(const u16x4*)(Cr + 4 * HH + j);
  u16x4 ghn = *(const u16x4*)(Cr + 5 * HH + j);
  f32x4 bir = *(const f32x4*)(b_ih + j);
  f32x4 biz = *(const f32x4*)(b_ih + HH + j);
  f32x4 bin = *(const f32x4*)(b_ih + 2 * HH + j);
  f32x4 bhr = *(const f32x4*)(b_hh + j);
  f32x4 bhz = *(const f32x4*)(b_hh + HH + j);
  f32x4 bhn = *(const f32x4*)(b_hh + 2 * HH + j);
  u16x4 hob = *(const u16x4*)(h_old_bf + (size_t)b * HH + j);
  f32x4 fw  = *(const f32x4*)(fcw + j);
  float s = 0.f;
#pragma unroll
  for (int e = 0; e < 4; ++e) {
    float r = 1.f / (1.f + expf(-(bf2f(gir[e]) + bir[e] + bf2f(ghr[e]) + bhr[e])));
    float z = 1.f / (1.f + expf(-(bf2f(giz[e]) + biz[e] + bf2f(ghz[e]) + bhz[e])));
    float n = tanhf(bf2f(gin[e]) + bin[e] + r * (bf2f(ghn[e]) + bhn[e]));
    float h = (1.f - z) * n + z * bf2f(hob[e]);
    s += h * fw[e];
  }
#pragma unroll
  for (int off = 32; off > 0; off >>= 1) s += __shfl_down(s, off);
  __shared__ float red[4];
  if ((threadIdx.x & 63) == 0) red[threadIdx.x >> 6] = s;
  __syncthreads();
  if (threadIdx.x == 0) {
    float v = red[0] + red[1] + red[2] + red[3];
    if ((blockIdx.x & 3) == 0) v += fcb[0];
    atomicAdd(&out[b], v);
  }
}

extern "C" void kernel_launch(void* const* d_in, const int* in_sizes, int n_in,
                              void* d_out, int out_size, void* d_ws, size_t ws_size,
                              hipStream_t stream)
{
  const float* feat = (const float*)d_in[0];
  const float* Wih  = (const float*)d_in[1];
  const float* bih  = (const float*)d_in[2];
  const float* Whh  = (const float*)d_in[3];
  const float* bhh  = (const float*)d_in[4];
  const float* fcw  = (const float*)d_in[5];
  const float* fcb  = (const float*)d_in[6];
  float* out = (float*)d_out;

  char* ws = (char*)d_ws;
  unsigned short* Wc   = (unsigned short*)ws;                    // 201326592 B
  unsigned short* Cbuf = (unsigned short*)(ws + 201326592);      // 201326592 B
  unsigned short* hb   = (unsigned short*)(ws + 402653184);      //  33554432 B
  // total: 436207616 B

  hipMemsetAsync(out, 0, (size_t)out_size * sizeof(float), stream);
  prep<<<NB_W + NB_C, 256, 0, stream>>>(Wih, Whh, feat, Wc, hb);

  gemm_bt<<<GRID_GEMM, 512, 0, stream>>>(hb, Wc, Cbuf);
  gru1<<<16384, 256, 0, stream>>>(Cbuf, feat, bih, bhh, hb);

  gemm_bt<<<GRID_GEMM, 512, 0, stream>>>(hb, Wc, Cbuf);
  gru2_fc<<<16384, 256, 0, stream>>>(Cbuf, hb, bih, bhh, fcw, fcb, out);
}